// Round 1
// baseline (62.673 us; speedup 1.0000x reference)
//
#include <hip/hip_runtime.h>

// DetectLayer decode, MI355X.
// Shapes: B=16, A=3, H=128, W=128, C=80, STRIDE=8.
// Locations: 16*3*128*128 = 786432.
// Outputs (concatenated float32):
//   p_bbox  [16, 49152, 4] -> 3,145,728 floats at offset 0
//   cls_idx [16, 49152]    ->   786,432 floats at offset 3,145,728 (stored as float)
//   confs   [16, 49152]    ->   786,432 floats at offset 3,932,160

#define NLOC   786432
#define HW_    (128 * 128)
#define AHW_   (3 * 128 * 128)
#define OFF_IDX  3145728
#define OFF_CONF 3932160

__device__ __forceinline__ float fast_sigmoid(float x) {
    return 1.0f / (1.0f + __expf(-x));
}

__global__ __launch_bounds__(256) void detect_kernel(
    const float* __restrict__ t_bbox,
    const float* __restrict__ conf_logits,
    const float* __restrict__ cls_logits,
    const float* __restrict__ anchors,
    float* __restrict__ out)
{
    int loc = blockIdx.x * blockDim.x + threadIdx.x;
    if (loc >= NLOC) return;

    int rem = loc % AHW_;        // index within a batch: a*H*W + h*W + w
    int a   = rem / HW_;
    int hw  = rem % HW_;
    int h   = hw >> 7;           // / 128
    int w   = hw & 127;          // % 128

    // ---- bbox decode (one coalesced float4 per thread) ----
    float4 t = *reinterpret_cast<const float4*>(t_bbox + (size_t)loc * 4);
    float s0 = fast_sigmoid(t.x);
    float s1 = fast_sigmoid(t.y);
    float s2 = fast_sigmoid(t.z);
    float s3 = fast_sigmoid(t.w);

    float aw = anchors[a * 2 + 0];
    float ah = anchors[a * 2 + 1];

    float px = (s0 * 2.0f - 0.5f + (float)w) * 8.0f;
    float py = (s1 * 2.0f - 0.5f + (float)h) * 8.0f;
    float tw = s2 * 2.0f;
    float th = s3 * 2.0f;
    float pw = tw * tw * aw;
    float ph = th * th * ah;

    // ---- class max/argmax over 80 logits (sigmoid is monotone:
    //      argmax(sigmoid(x)) == argmax(x), max(sigmoid) == sigmoid(max)) ----
    const float4* cp = reinterpret_cast<const float4*>(cls_logits + (size_t)loc * 80);
    float m = -INFINITY;
    int mi = 0;
    #pragma unroll
    for (int i = 0; i < 20; ++i) {
        float4 v = cp[i];
        if (v.x > m) { m = v.x; mi = i * 4 + 0; }
        if (v.y > m) { m = v.y; mi = i * 4 + 1; }
        if (v.z > m) { m = v.z; mi = i * 4 + 2; }
        if (v.w > m) { m = v.w; mi = i * 4 + 3; }
    }

    float pconf = fast_sigmoid(conf_logits[loc]);
    float pcls  = fast_sigmoid(m);

    // ---- writes ----
    reinterpret_cast<float4*>(out)[loc] = make_float4(px, py, pw, ph);
    out[OFF_IDX  + loc] = (float)mi;
    out[OFF_CONF + loc] = pconf * pcls;
}

extern "C" void kernel_launch(void* const* d_in, const int* in_sizes, int n_in,
                              void* d_out, int out_size, void* d_ws, size_t ws_size,
                              hipStream_t stream) {
    const float* t_bbox      = (const float*)d_in[0];
    const float* conf_logits = (const float*)d_in[1];
    const float* cls_logits  = (const float*)d_in[2];
    const float* anchors     = (const float*)d_in[3];
    float* out = (float*)d_out;

    const int threads = 256;
    const int blocks  = (NLOC + threads - 1) / threads;  // 3072
    detect_kernel<<<blocks, threads, 0, stream>>>(
        t_bbox, conf_logits, cls_logits, anchors, out);
}

// Round 2
// 46.640 us; speedup vs baseline: 1.3437x; 1.3437x over previous
//
#include <hip/hip_runtime.h>

// DetectLayer decode, MI355X (gfx950).
// Shapes: B=16, A=3, H=128, W=128, C=80, STRIDE=8. NLOC = 786432.
// Outputs (concatenated float32):
//   p_bbox  [16,49152,4] -> 3,145,728 floats @ 0
//   cls_idx [16,49152]   ->   786,432 floats @ 3,145,728 (float-encoded int)
//   confs   [16,49152]   ->   786,432 floats @ 3,932,160
//
// Layout strategy: 4 lanes per location for the 80-class max/argmax so each
// vector load instruction covers contiguous 64B segments (16 lines/instr vs 64
// for thread-per-location). Decode/write phase re-mapped through LDS so the
// bbox float4 loads and all stores are perfectly coalesced.

#define NLOC   786432
#define HW_    (128 * 128)
#define AHW_   (3 * 128 * 128)
#define OFF_IDX  3145728
#define OFF_CONF 3932160

__device__ __forceinline__ float fast_sigmoid(float x) {
    return 1.0f / (1.0f + __expf(-x));
}

__global__ __launch_bounds__(256) void detect_kernel(
    const float* __restrict__ t_bbox,
    const float* __restrict__ conf_logits,
    const float* __restrict__ cls_logits,
    const float* __restrict__ anchors,
    float* __restrict__ out)
{
    __shared__ float s_m[64];
    __shared__ int   s_mi[64];

    const int wave = threadIdx.x >> 6;   // 0..3
    const int lane = threadIdx.x & 63;
    const int g    = lane >> 2;          // group within wave: 0..15
    const int k    = lane & 3;           // sub-lane within group

    const int block_base = blockIdx.x * 64;         // 64 locations per block
    const int loc = block_base + wave * 16 + g;

    // ---- class max/argmax: 4 lanes x 5 float4 each cover 80 classes ----
    // lane (g,k), iter i reads bytes [loc*320 + i*64 + k*16, +16):
    // per instruction the wave touches 16 contiguous 64B segments.
    const float4* cp = reinterpret_cast<const float4*>(cls_logits) + (size_t)loc * 20;
    float m = -INFINITY;
    int   mi = 0;
    #pragma unroll
    for (int i = 0; i < 5; ++i) {
        float4 v = cp[i * 4 + k];
        int ci = (i * 4 + k) * 4;        // ascending within each lane -> '>' keeps first max
        if (v.x > m) { m = v.x; mi = ci + 0; }
        if (v.y > m) { m = v.y; mi = ci + 1; }
        if (v.z > m) { m = v.z; mi = ci + 2; }
        if (v.w > m) { m = v.w; mi = ci + 3; }
    }
    // reduce across the 4 sub-lanes; tie-break on lower class index (jnp.argmax)
    #pragma unroll
    for (int off = 1; off <= 2; off <<= 1) {
        float om  = __shfl_xor(m,  off, 64);
        int   omi = __shfl_xor(mi, off, 64);
        if (om > m || (om == m && omi < mi)) { m = om; mi = omi; }
    }
    if (k == 0) {
        s_m [wave * 16 + g] = m;
        s_mi[wave * 16 + g] = mi;
    }
    __syncthreads();

    // ---- decode + writes: threads 0..63 handle the block's 64 locations ----
    if (threadIdx.x < 64) {
        const int t    = threadIdx.x;
        const int loc2 = block_base + t;

        int rem = loc2 % AHW_;
        int a   = rem / HW_;
        int hw  = rem % HW_;
        int h   = hw >> 7;
        int w   = hw & 127;

        float4 tb = *reinterpret_cast<const float4*>(t_bbox + (size_t)loc2 * 4);
        float s0 = fast_sigmoid(tb.x);
        float s1 = fast_sigmoid(tb.y);
        float s2 = fast_sigmoid(tb.z);
        float s3 = fast_sigmoid(tb.w);

        float aw = anchors[a * 2 + 0];
        float ah = anchors[a * 2 + 1];

        float px = (s0 * 2.0f - 0.5f + (float)w) * 8.0f;
        float py = (s1 * 2.0f - 0.5f + (float)h) * 8.0f;
        float tw = s2 * 2.0f;
        float th = s3 * 2.0f;
        float pw = tw * tw * aw;
        float ph = th * th * ah;

        float pconf = fast_sigmoid(conf_logits[loc2]);
        float pcls  = fast_sigmoid(s_m[t]);

        reinterpret_cast<float4*>(out)[loc2] = make_float4(px, py, pw, ph);
        out[OFF_IDX  + loc2] = (float)s_mi[t];
        out[OFF_CONF + loc2] = pconf * pcls;
    }
}

extern "C" void kernel_launch(void* const* d_in, const int* in_sizes, int n_in,
                              void* d_out, int out_size, void* d_ws, size_t ws_size,
                              hipStream_t stream) {
    const float* t_bbox      = (const float*)d_in[0];
    const float* conf_logits = (const float*)d_in[1];
    const float* cls_logits  = (const float*)d_in[2];
    const float* anchors     = (const float*)d_in[3];
    float* out = (float*)d_out;

    const int threads = 256;
    const int blocks  = NLOC / 64;   // 12288 blocks, 64 locations each
    detect_kernel<<<blocks, threads, 0, stream>>>(
        t_bbox, conf_logits, cls_logits, anchors, out);
}